// Round 1
// baseline (435.140 us; speedup 1.0000x reference)
//
#include <hip/hip_runtime.h>
#include <math.h>

#define S_LEN 1024
#define CAP 1024
#define EPS 1e-6f

// Workspace layout (bytes):
//   assign : int [32*1024]          @ 0        (131072)
//   qcnt   : int [32*64]            @ 131072   (8192)
//   qlist  : int [32*64*CAP]        @ 139264   (8388608)
//   qw     : float [32*64*CAP]      @ 8527872  (8388608)
// total ~16.1 MB

__device__ __forceinline__ void wave_argmax(float& bv, int& bi) {
    #pragma unroll
    for (int off = 1; off < 64; off <<= 1) {
        float ov = __shfl_xor(bv, off, 64);
        int   oi = __shfl_xor(bi, off, 64);
        if (ov > bv || (ov == bv && oi < bi)) { bv = ov; bi = oi; }
    }
}

// one wave per key: bank = argmax_d |k_d| (first occurrence), d in [0,64)
__global__ __launch_bounds__(256) void k_assign(const float* __restrict__ keys,
                                                int* __restrict__ assign) {
    int gid  = blockIdx.x * 4 + (threadIdx.x >> 6);   // key index over BH*S
    int lane = threadIdx.x & 63;
    float bv = fabsf(keys[(size_t)gid * 64 + lane]);
    int bi = lane;
    wave_argmax(bv, bi);
    if (lane == 0) assign[gid] = bi;
}

// one wave per query: emulate top-16 over the duplicated 128-entry score array
// exactly (stable tie-break), softmax over all 16, scatter entries with idx<64.
__global__ __launch_bounds__(256) void k_topk(const float* __restrict__ queries,
                                              int* __restrict__ qcnt,
                                              int* __restrict__ qlist,
                                              float* __restrict__ qw) {
    int gid  = blockIdx.x * 4 + (threadIdx.x >> 6);   // query index over BH*S
    int lane = threadIdx.x & 63;
    float aval = fabsf(queries[(size_t)gid * 64 + lane]);
    int cnt = 2;                                      // copies left for this lane
    float mv[16]; int mi[16];
    #pragma unroll
    for (int i = 0; i < 16; ++i) {
        float bv = (cnt > 0) ? aval : -1.0f;
        int   bi = (cnt == 2) ? lane : (lane + 64);
        wave_argmax(bv, bi);
        mv[i] = bv; mi[i] = bi;
        if ((bi & 63) == lane) cnt--;                 // winner consumes one copy
    }
    if (lane == 0) {
        float m0 = mv[0], sum = 0.f, e[16];
        #pragma unroll
        for (int i = 0; i < 16; ++i) { e[i] = expf(mv[i] - m0); sum += e[i]; }
        float inv = 1.0f / sum;
        int bh = gid >> 10, s = gid & 1023;
        #pragma unroll
        for (int i = 0; i < 16; ++i) {
            if (mi[i] < 64) {                         // idx>=64 banks contribute 0
                int g = bh * 64 + mi[i];
                int pos = atomicAdd(&qcnt[g], 1);
                qlist[(size_t)g * CAP + pos] = s;
                qw[(size_t)g * CAP + pos]    = e[i] * inv;
            }
        }
    }
}

// one block per (bh, bank): build M (64x64) + z in LDS, then process this
// bank's query list in batches of 64 (16 queries per wave), atomic-add output.
__global__ __launch_bounds__(256) void k_main(const float* __restrict__ keys,
                                              const float* __restrict__ values,
                                              const float* __restrict__ queries,
                                              const int* __restrict__ assign,
                                              const int* __restrict__ qcnt,
                                              const int* __restrict__ qlist,
                                              const float* __restrict__ qw,
                                              float* __restrict__ out) {
    const int g    = blockIdx.x;       // 0..2047
    const int bh   = g >> 6;
    const int bank = g & 63;
    const int t    = threadIdx.x;
    const int lane = t & 63;
    const int grp  = t >> 6;

    __shared__ int   s_cnt;
    __shared__ int   s_match[128];
    __shared__ float k_st[4][64];
    __shared__ float v_st[4][64];
    __shared__ float M4[64 * 64];      // XOR-swizzled float4 tiles, 16 KB
    __shared__ float z_s[64];
    __shared__ float Qs[64 * 64];      // 64 staged queries, row-major
    __shared__ float w_s[64];
    __shared__ int   sq_s[64];

    const int nq = qcnt[g];
    if (nq == 0) return;

    if (t == 0) s_cnt = 0;
    __syncthreads();
    const int* as = assign + bh * S_LEN;
    for (int s = t; s < S_LEN; s += 256) {
        if (as[s] == bank) {
            int p = atomicAdd(&s_cnt, 1);
            if (p < 128) s_match[p] = s;
        }
    }
    __syncthreads();
    const int nm = min(s_cnt, 128);
    if (nm == 0) return;               // M = 0, z = 0 -> contribution exactly 0

    // ---- build M[dv][dk] = sum_s v[dv]*k[dk], z[dk] = sum_s k[dk] ----
    float acc[16];
    #pragma unroll
    for (int m = 0; m < 16; ++m) acc[m] = 0.f;
    float zacc = 0.f;
    const float* kb = keys   + (size_t)bh * S_LEN * 64;
    const float* vb = values + (size_t)bh * S_LEN * 64;
    for (int base = 0; base < nm; base += 4) {
        __syncthreads();               // protect k_st/v_st reuse
        if (base + grp < nm) {
            int s = s_match[base + grp];
            k_st[grp][lane] = kb[(size_t)s * 64 + lane];
            v_st[grp][lane] = vb[(size_t)s * 64 + lane];
        }
        __syncthreads();
        int lim = min(4, nm - base);
        for (int jj = 0; jj < lim; ++jj) {
            float kv = k_st[jj][lane];                 // thread's dk = lane
            #pragma unroll
            for (int m = 0; m < 16; ++m)               // thread's dv = grp*16+m
                acc[m] += v_st[jj][grp * 16 + m] * kv; // broadcast read
        }
        if (t < 64)
            for (int jj = 0; jj < lim; ++jj) zacc += k_st[jj][t];
    }
    __syncthreads();
    #pragma unroll
    for (int m = 0; m < 16; ++m) {
        int dv = grp * 16 + m;
        int cs = (lane >> 2) ^ (dv & 15);              // chunk swizzle
        M4[dv * 64 + cs * 4 + (lane & 3)] = acc[m];
    }
    if (t < 64) z_s[t] = zacc;
    __syncthreads();

    // ---- query phase ----
    const float*  qb  = queries + (size_t)bh * S_LEN * 64;
    float*        ob  = out     + (size_t)bh * S_LEN * 64;
    const int*    ql  = qlist + (size_t)g * CAP;
    const float*  qwp = qw    + (size_t)g * CAP;
    const float4* M4v = (const float4*)M4;
    const float4* Q4  = (const float4*)Qs;

    for (int qbase = 0; qbase < nq; qbase += 64) {
        const int nb = min(64, nq - qbase);
        __syncthreads();               // protect Qs/w_s/sq_s reuse
        #pragma unroll
        for (int ii = 0; ii < 16; ++ii) {
            int j = grp * 16 + ii;
            if (j < nb) {
                int s = ql[qbase + j];
                Qs[j * 64 + lane] = qb[(size_t)s * 64 + lane];
            }
        }
        if (t < nb) { sq_s[t] = ql[qbase + t]; w_s[t] = qwp[qbase + t]; }
        __syncthreads();

        const int j0 = grp * 16;       // this wave's 16 queries
        float den[16];
        #pragma unroll
        for (int jj = 0; jj < 16; ++jj) {
            float p = (j0 + jj < nb) ? z_s[lane] * Qs[(j0 + jj) * 64 + lane] : 0.f;
            #pragma unroll
            for (int off = 1; off < 64; off <<= 1) p += __shfl_xor(p, off, 64);
            den[jj] = p;
        }
        float qa[16];
        #pragma unroll
        for (int jj = 0; jj < 16; ++jj) qa[jj] = 0.f;
        #pragma unroll 4
        for (int c = 0; c < 16; ++c) { // dk quads; lane = dv (output row)
            float4 mm = M4v[lane * 16 + (c ^ (lane & 15))];
            #pragma unroll
            for (int jj = 0; jj < 16; ++jj) {
                float4 qq = Q4[(j0 + jj) * 16 + c];    // broadcast
                qa[jj] += mm.x * qq.x + mm.y * qq.y + mm.z * qq.z + mm.w * qq.w;
            }
        }
        #pragma unroll
        for (int jj = 0; jj < 16; ++jj) {
            if (j0 + jj < nb) {
                float val = w_s[j0 + jj] * qa[jj] / (den[jj] + EPS);
                unsafeAtomicAdd(&ob[(size_t)sq_s[j0 + jj] * 64 + lane], val);
            }
        }
    }
}

extern "C" void kernel_launch(void* const* d_in, const int* in_sizes, int n_in,
                              void* d_out, int out_size, void* d_ws, size_t ws_size,
                              hipStream_t stream) {
    const float* keys    = (const float*)d_in[0];
    const float* values  = (const float*)d_in[1];
    const float* queries = (const float*)d_in[2];
    char* ws = (char*)d_ws;
    int*   assign = (int*)(ws);
    int*   qcnt   = (int*)(ws + 131072);
    int*   qlist  = (int*)(ws + 139264);
    float* qwp    = (float*)(ws + 8527872);

    hipMemsetAsync(qcnt, 0, 8192, stream);
    hipMemsetAsync(d_out, 0, (size_t)out_size * sizeof(float), stream);
    k_assign<<<8192, 256, 0, stream>>>(keys, assign);
    k_topk  <<<8192, 256, 0, stream>>>(queries, qcnt, qlist, qwp);
    k_main  <<<2048, 256, 0, stream>>>(keys, values, queries, assign, qcnt, qlist, qwp,
                                       (float*)d_out);
}

// Round 2
// 310.003 us; speedup vs baseline: 1.4037x; 1.4037x over previous
//
#include <hip/hip_runtime.h>
#include <math.h>

#define S_LEN 1024
#define CAP 1024
#define EPS 1e-6f

// Workspace layout (bytes):
//   assign : int [32*1024]          @ 0        (131072)
//   qcnt   : int [32*64]            @ 131072   (8192)
//   qlist  : int [32*64*CAP]        @ 139264   (8388608)
//   qw     : float [32*64*CAP]      @ 8527872  (8388608)

__device__ __forceinline__ void wave_argmax(float& bv, int& bi) {
    #pragma unroll
    for (int off = 1; off < 64; off <<= 1) {
        float ov = __shfl_xor(bv, off, 64);
        int   oi = __shfl_xor(bi, off, 64);
        if (ov > bv || (ov == bv && oi < bi)) { bv = ov; bi = oi; }
    }
}

// one wave per key: bank = argmax_d |k_d| (first occurrence), d in [0,64)
__global__ __launch_bounds__(256) void k_assign(const float* __restrict__ keys,
                                                int* __restrict__ assign) {
    int gid  = blockIdx.x * 4 + (threadIdx.x >> 6);
    int lane = threadIdx.x & 63;
    float bv = fabsf(keys[(size_t)gid * 64 + lane]);
    int bi = lane;
    wave_argmax(bv, bi);
    if (lane == 0) assign[gid] = bi;
}

// one wave per query. Top-16 over the duplicated 128-entry array == extraction
// over DISTINCT dims (each consumes up to 2 of the 16 slots), exact under ties
// via ballot groups: a tie group of g dims occupies its g low-idx copies first,
// then its g high-idx copies. Low copies (idx<64) contribute; high copies only
// enter the softmax sum. Scatter parallelized across lanes.
__global__ __launch_bounds__(256) void k_topk(const float* __restrict__ queries,
                                              int* __restrict__ qcnt,
                                              int* __restrict__ qlist,
                                              float* __restrict__ qw) {
    int gid  = blockIdx.x * 4 + (threadIdx.x >> 6);
    int lane = threadIdx.x & 63;
    float aval = fabsf(queries[(size_t)gid * 64 + lane]);
    bool alive = true, contrib = false, first = true;
    int slots = 16;
    float m0 = 0.f, sumexp = 0.f, my_e = 0.f;
    while (slots > 0) {
        float bv = alive ? aval : -1.0f;
        int   bi = alive ? lane : 64;
        wave_argmax(bv, bi);
        if (first) { m0 = bv; first = false; }
        float e = expf(bv - m0);
        unsigned long long tied = __ballot(alive && (aval == bv));
        int gc = __popcll(tied);
        int L = min(slots, gc);
        int H = min(slots - L, gc);
        sumexp += (float)(L + H) * e;
        if (alive && (aval == bv)) {
            int rank = __popcll(tied & ((1ull << lane) - 1ull));
            if (rank < L) { contrib = true; my_e = e; }
            alive = false;
        }
        slots -= L + H;
    }
    if (contrib) {
        int bh = gid >> 10, s = gid & 1023;
        int g = bh * 64 + lane;                  // dim == lane
        int pos = atomicAdd(&qcnt[g], 1);
        qlist[(size_t)g * CAP + pos] = s;
        qw[(size_t)g * CAP + pos]    = my_e / sumexp;
    }
}

// one block per (bh, bank, chunk): build M (64x64) + z in LDS, then process
// this chunk's share of the bank's query list in batches of 64.
__global__ __launch_bounds__(256) void k_main(const float* __restrict__ keys,
                                              const float* __restrict__ values,
                                              const float* __restrict__ queries,
                                              const int* __restrict__ assign,
                                              const int* __restrict__ qcnt,
                                              const int* __restrict__ qlist,
                                              const float* __restrict__ qw,
                                              float* __restrict__ out) {
    const int gc    = blockIdx.x;      // 0..4095
    const int g     = gc >> 1;
    const int chunk = gc & 1;
    const int bh   = g >> 6;
    const int bank = g & 63;
    const int t    = threadIdx.x;
    const int lane = t & 63;
    const int grp  = t >> 6;

    __shared__ int   s_cnt;
    __shared__ int   s_match[128];
    __shared__ float k_st[8][64];
    __shared__ float v_st[8][64];
    __shared__ float M4[64 * 64];      // XOR-swizzled float4 tiles, 16 KB
    __shared__ float z_s[64];
    __shared__ float Qs[64 * 64];      // swizzled float4 rows, 16 KB
    __shared__ float w_s[64];
    __shared__ int   sq_s[64];

    const int nq_all = qcnt[g];
    if (nq_all == 0) return;
    const int half = (nq_all + 1) >> 1;
    const int q_lo = chunk * half;
    const int nq   = min(nq_all, q_lo + half) - q_lo;
    if (nq <= 0) return;

    if (t == 0) s_cnt = 0;
    __syncthreads();
    const int* as = assign + bh * S_LEN;
    for (int s = t; s < S_LEN; s += 256) {
        if (as[s] == bank) {
            int p = atomicAdd(&s_cnt, 1);
            if (p < 128) s_match[p] = s;
        }
    }
    __syncthreads();
    const int nm = min(s_cnt, 128);
    if (nm == 0) return;               // M = 0, z = 0 -> contribution exactly 0

    // ---- build M[dv][dk] = sum_s v[dv]*k[dk], z[dk] = sum_s k[dk] ----
    float acc[16];
    #pragma unroll
    for (int m = 0; m < 16; ++m) acc[m] = 0.f;
    float zacc = 0.f;
    const float* kb = keys   + (size_t)bh * S_LEN * 64;
    const float* vb = values + (size_t)bh * S_LEN * 64;
    for (int base = 0; base < nm; base += 8) {
        __syncthreads();
        #pragma unroll
        for (int rr = 0; rr < 2; ++rr) {
            int row = grp + rr * 4;
            if (base + row < nm) {
                int s = s_match[base + row];
                k_st[row][lane] = kb[(size_t)s * 64 + lane];
                v_st[row][lane] = vb[(size_t)s * 64 + lane];
            }
        }
        __syncthreads();
        int lim = min(8, nm - base);
        for (int jj = 0; jj < lim; ++jj) {
            float kv = k_st[jj][lane];                 // thread's dk = lane
            #pragma unroll
            for (int m = 0; m < 16; ++m)               // thread's dv = grp*16+m
                acc[m] += v_st[jj][grp * 16 + m] * kv; // broadcast read
        }
        if (t < 64)
            for (int jj = 0; jj < lim; ++jj) zacc += k_st[jj][t];
    }
    __syncthreads();
    #pragma unroll
    for (int m = 0; m < 16; ++m) {
        int dv = grp * 16 + m;
        int cs = (lane >> 2) ^ (dv & 15);              // chunk swizzle
        M4[dv * 64 + cs * 4 + (lane & 3)] = acc[m];
    }
    if (t < 64) z_s[t] = zacc;
    __syncthreads();

    // ---- query phase ----
    const float*  qb  = queries + (size_t)bh * S_LEN * 64;
    float*        ob  = out     + (size_t)bh * S_LEN * 64;
    const int*    ql  = qlist + (size_t)g * CAP + q_lo;
    const float*  qwp = qw    + (size_t)g * CAP + q_lo;
    const float4* M4v = (const float4*)M4;
    float4*       Q4w = (float4*)Qs;
    const float4* Q4  = (const float4*)Qs;

    for (int qbase = 0; qbase < nq; qbase += 64) {
        const int nb = min(64, nq - qbase);
        __syncthreads();               // protect Qs/w_s/sq_s reuse
        if (t < nb) { sq_s[t] = ql[qbase + t]; w_s[t] = qwp[qbase + t]; }
        // stage queries: float4, XOR-swizzled rows (row j, quad c at j*16+(c^j))
        #pragma unroll
        for (int pp = 0; pp < 4; ++pp) {
            int p = t + pp * 256;      // 0..1023
            int j = p >> 4, c = p & 15;
            if (j < nb) {
                int s = ql[qbase + j];
                const float4* src = (const float4*)(qb + (size_t)s * 64);
                Q4w[j * 16 + (c ^ (j & 15))] = src[c];
            }
        }
        __syncthreads();

        const int j0 = grp * 16;       // this wave's 16 queries
        // den in fp64: lane r*16+q16 handles quads 4r..4r+3 of query j0+q16
        double dden = 0.0;
        {
            int q16 = lane & 15, r = lane >> 4;
            int j = j0 + q16;
            #pragma unroll
            for (int cc = 0; cc < 4; ++cc) {
                int c = 4 * r + cc;
                float4 qq = Q4[j * 16 + (c ^ q16)];
                float4 zz = *(const float4*)&z_s[4 * c];
                dden += (double)zz.x * qq.x + (double)zz.y * qq.y
                      + (double)zz.z * qq.z + (double)zz.w * qq.w;
            }
            dden += __shfl_xor(dden, 16, 64);
            dden += __shfl_xor(dden, 32, 64);
        }

        float qa[16];
        #pragma unroll
        for (int jj = 0; jj < 16; ++jj) qa[jj] = 0.f;
        #pragma unroll 4
        for (int c = 0; c < 16; ++c) { // dk quads; lane = dv (output row)
            float4 mm = M4v[lane * 16 + (c ^ (lane & 15))];
            #pragma unroll
            for (int jj = 0; jj < 16; ++jj) {
                float4 qq = Q4[(j0 + jj) * 16 + (c ^ jj)];   // broadcast
                qa[jj] += mm.x * qq.x + mm.y * qq.y + mm.z * qq.z + mm.w * qq.w;
            }
        }
        #pragma unroll
        for (int jj = 0; jj < 16; ++jj) {
            if (j0 + jj < nb) {
                double dj = __shfl(dden, jj, 64);      // lane jj holds query j0+jj
                float denf = (float)(dj + (double)EPS);
                float val = w_s[j0 + jj] * qa[jj] / denf;
                unsafeAtomicAdd(&ob[(size_t)sq_s[j0 + jj] * 64 + lane], val);
            }
        }
    }
}

extern "C" void kernel_launch(void* const* d_in, const int* in_sizes, int n_in,
                              void* d_out, int out_size, void* d_ws, size_t ws_size,
                              hipStream_t stream) {
    const float* keys    = (const float*)d_in[0];
    const float* values  = (const float*)d_in[1];
    const float* queries = (const float*)d_in[2];
    char* ws = (char*)d_ws;
    int*   assign = (int*)(ws);
    int*   qcnt   = (int*)(ws + 131072);
    int*   qlist  = (int*)(ws + 139264);
    float* qwp    = (float*)(ws + 8527872);

    hipMemsetAsync(qcnt, 0, 8192, stream);
    hipMemsetAsync(d_out, 0, (size_t)out_size * sizeof(float), stream);
    k_assign<<<8192, 256, 0, stream>>>(keys, assign);
    k_topk  <<<8192, 256, 0, stream>>>(queries, qcnt, qlist, qwp);
    k_main  <<<4096, 256, 0, stream>>>(keys, values, queries, assign, qcnt, qlist, qwp,
                                       (float*)d_out);
}

// Round 3
// 243.913 us; speedup vs baseline: 1.7840x; 1.2710x over previous
//
#include <hip/hip_runtime.h>
#include <math.h>

#define S_LEN 1024
#define EPS 1e-6f

typedef __attribute__((ext_vector_type(8)))  short bf16x8;
typedef __attribute__((ext_vector_type(16))) float float16v;

// Workspace layout (bytes):
//   kcnt  : int    [2048]        @ 0
//   qcnt  : int    [2048]        @ 8192
//   klist : ushort [2048*1024]   @ 16384      (4 MB)
//   qpair : int2   [2048*1024]   @ 4210688    (16 MB)

__device__ __forceinline__ void wave_argmax(float& bv, int& bi) {
    #pragma unroll
    for (int off = 1; off < 64; off <<= 1) {
        float ov = __shfl_xor(bv, off, 64);
        int   oi = __shfl_xor(bi, off, 64);
        if (ov > bv || (ov == bv && oi < bi)) { bv = ov; bi = oi; }
    }
}

__device__ __forceinline__ unsigned short f2bf(float f) {
    unsigned int u = __float_as_uint(f);
    unsigned int r = (u + 0x7fffu + ((u >> 16) & 1u)) >> 16;
    return (unsigned short)r;
}

__device__ __forceinline__ bf16x8 pack8(float4 a, float4 b) {
    bf16x8 r;
    r[0] = (short)f2bf(a.x); r[1] = (short)f2bf(a.y);
    r[2] = (short)f2bf(a.z); r[3] = (short)f2bf(a.w);
    r[4] = (short)f2bf(b.x); r[5] = (short)f2bf(b.y);
    r[6] = (short)f2bf(b.z); r[7] = (short)f2bf(b.w);
    return r;
}

// one wave per key: bank = argmax_d |k_d|; scatter s into per-(bh,bank) list
__global__ __launch_bounds__(256) void k_assign(const float* __restrict__ keys,
                                                int* __restrict__ kcnt,
                                                unsigned short* __restrict__ klist) {
    int gid  = blockIdx.x * 4 + (threadIdx.x >> 6);
    int lane = threadIdx.x & 63;
    float bv = fabsf(keys[(size_t)gid * 64 + lane]);
    int bi = lane;
    wave_argmax(bv, bi);
    if (lane == 0) {
        int g = (gid >> 10) * 64 + bi;
        int p = atomicAdd(&kcnt[g], 1);
        klist[(size_t)g * 1024 + p] = (unsigned short)(gid & 1023);
    }
}

// one wave per query: exact duplicated-top-16 via ballot extraction (tie groups
// fill low-idx copies first); scatter (s, w) pairs, parallel across lanes.
__global__ __launch_bounds__(256) void k_topk(const float* __restrict__ queries,
                                              int* __restrict__ qcnt,
                                              int2* __restrict__ qpair) {
    int gid  = blockIdx.x * 4 + (threadIdx.x >> 6);
    int lane = threadIdx.x & 63;
    float aval = fabsf(queries[(size_t)gid * 64 + lane]);
    bool alive = true, contrib = false, first = true;
    int slots = 16;
    float m0 = 0.f, sumexp = 0.f, my_e = 0.f;
    while (slots > 0) {
        float bv = alive ? aval : -1.0f;
        wave_argmax(bv, *(int*)&slots == 0 ? *(int*)&slots : *(&slots));  // placeholder avoided below
        // (real argmax below)
        slots = slots;  // no-op
        break;
    }
    // --- rewritten cleanly (the loop above is dead; compiler removes) ---
    alive = true; contrib = false; first = true;
    slots = 16; m0 = 0.f; sumexp = 0.f; my_e = 0.f;
    while (slots > 0) {
        float bv = alive ? aval : -1.0f;
        int   bi = alive ? lane : 64;
        wave_argmax(bv, bi);
        if (first) { m0 = bv; first = false; }
        float e = expf(bv - m0);
        unsigned long long tied = __ballot(alive && (aval == bv));
        int gc = __popcll(tied);
        int L = min(slots, gc);
        int H = min(slots - L, gc);
        sumexp += (float)(L + H) * e;
        if (alive && (aval == bv)) {
            int rank = __popcll(tied & ((1ull << lane) - 1ull));
            if (rank < L) { contrib = true; my_e = e; }
            alive = false;
        }
        slots -= L + H;
    }
    if (contrib) {
        int bh = gid >> 10, s = gid & 1023;
        int g = bh * 64 + lane;
        int pos = atomicAdd(&qcnt[g], 1);
        int2 pr; pr.x = s; pr.y = __float_as_int(my_e / sumexp);
        qpair[(size_t)g * 1024 + pos] = pr;
    }
}

// one block per (bh, bank, chunk): build M(64x64)->bf16 LDS + z fp32, then per
// 64-query batch: stage Q as bf16 (den folded into staging, fp64), 4 MFMAs per
// wave, transpose O through LDS, coalesced atomic flush.
__global__ __launch_bounds__(256) void k_main(const float* __restrict__ keys,
                                              const float* __restrict__ values,
                                              const float* __restrict__ queries,
                                              const int* __restrict__ kcnt,
                                              const unsigned short* __restrict__ klist,
                                              const int* __restrict__ qcnt,
                                              const int2* __restrict__ qpair,
                                              float* __restrict__ out) {
    const int gc    = blockIdx.x;      // 0..4095
    const int g     = gc >> 1;
    const int chunk = gc & 1;
    const int bh    = g >> 6;
    const int t     = threadIdx.x;
    const int lane  = t & 63;
    const int grp   = t >> 6;

    __shared__ alignas(16) unsigned short M_bf[64 * 64];   // swizzled 16B chunks
    __shared__ alignas(16) unsigned short Q_bf[64 * 64];   // swizzled 16B chunks
    __shared__ alignas(16) float Ou[64 * 66];              // O transpose / kv staging
    __shared__ float  z_s[64];
    __shared__ double den_s[64];
    __shared__ float  w_s[64];
    __shared__ int    sq_s[64];

    const int nq_all = qcnt[g];
    if (nq_all == 0) return;
    const int half = (nq_all + 1) >> 1;
    const int q_lo = chunk * half;
    const int nq   = min(nq_all, q_lo + half) - q_lo;
    if (nq <= 0) return;
    const int nm = kcnt[g];
    if (nm == 0) return;               // M=0, z=0 -> exact zero contribution

    // ---- build M[dv][dk] = sum_s v[dv]*k[dk], z[dk] = sum_s k[dk] (fp32) ----
    float* kst = Ou;                   // [8][64]
    float* vst = Ou + 512;             // [8][64]
    float acc[16];
    #pragma unroll
    for (int m = 0; m < 16; ++m) acc[m] = 0.f;
    float zacc = 0.f;
    const float* kb = keys   + (size_t)bh * S_LEN * 64;
    const float* vb = values + (size_t)bh * S_LEN * 64;
    const unsigned short* kl = klist + (size_t)g * 1024;
    for (int base = 0; base < nm; base += 8) {
        __syncthreads();
        #pragma unroll
        for (int rr = 0; rr < 2; ++rr) {
            int row = grp + rr * 4;
            if (base + row < nm) {
                int s = kl[base + row];
                kst[row * 64 + lane] = kb[(size_t)s * 64 + lane];
                vst[row * 64 + lane] = vb[(size_t)s * 64 + lane];
            }
        }
        __syncthreads();
        int lim = min(8, nm - base);
        for (int jj = 0; jj < lim; ++jj) {
            float kv = kst[jj * 64 + lane];            // dk = lane
            #pragma unroll
            for (int m = 0; m < 16; ++m)               // dv = grp*16+m
                acc[m] += vst[jj * 64 + grp * 16 + m] * kv;
        }
        if (t < 64)
            for (int jj = 0; jj < lim; ++jj) zacc += kst[jj * 64 + t];
    }
    // write M as bf16, row-major [dv][dk], 16B-chunk XOR swizzle
    #pragma unroll
    for (int m = 0; m < 16; ++m) {
        int dv = grp * 16 + m;
        M_bf[dv * 64 + (((lane >> 3) ^ (dv & 7)) << 3) + (lane & 7)] = f2bf(acc[m]);
    }
    if (t < 64) z_s[t] = zacc;

    // ---- query phase ----
    const float* qb  = queries + (size_t)bh * S_LEN * 64;
    float*       ob  = out     + (size_t)bh * S_LEN * 64;
    const int2*  ql2 = qpair + (size_t)g * 1024 + q_lo;

    const int dvh = grp >> 1, jh = grp & 1;            // wave's 32x32 tile

    for (int qbase = 0; qbase < nq; qbase += 64) {
        const int nb = min(64, nq - qbase);
        __syncthreads();               // M_bf/z_s visible; prev flush done

        // stage: thread -> (query j = t>>2, 16-float slice c4 = t&3)
        {
            int j = t >> 2, c4 = t & 3;
            bf16x8 p0 = {}, p1 = {};
            double d = 0.0;
            if (j < nb) {
                int s = ql2[qbase + j].x;
                const float4* src = (const float4*)(qb + (size_t)s * 64 + c4 * 16);
                float4 f0 = src[0], f1 = src[1], f2 = src[2], f3 = src[3];
                p0 = pack8(f0, f1);
                p1 = pack8(f2, f3);
                const float4* zz4 = (const float4*)&z_s[c4 * 16];
                float4 z0 = zz4[0], z1 = zz4[1], z2 = zz4[2], z3 = zz4[3];
                d  = (double)z0.x * f0.x + (double)z0.y * f0.y + (double)z0.z * f0.z + (double)z0.w * f0.w;
                d += (double)z1.x * f1.x + (double)z1.y * f1.y + (double)z1.z * f1.z + (double)z1.w * f1.w;
                d += (double)z2.x * f2.x + (double)z2.y * f2.y + (double)z2.z * f2.z + (double)z2.w * f2.w;
                d += (double)z3.x * f3.x + (double)z3.y * f3.y + (double)z3.z * f3.z + (double)z3.w * f3.w;
            }
            int c0 = c4 * 2;
            *(bf16x8*)&Q_bf[j * 64 + ((c0 ^ (j & 7)) << 3)]       = p0;
            *(bf16x8*)&Q_bf[j * 64 + (((c0 + 1) ^ (j & 7)) << 3)] = p1;
            d += __shfl_xor(d, 1, 64);
            d += __shfl_xor(d, 2, 64);
            if ((t & 3) == 0) den_s[j] = d;
            if (t < 64) {
                if (t < nb) {
                    int2 pr = ql2[qbase + t];
                    sq_s[t] = pr.x; w_s[t] = __int_as_float(pr.y);
                } else { sq_s[t] = 0; w_s[t] = 0.f; }
            }
        }
        __syncthreads();

        // MFMA: O[dv][j] = sum_dk M[dv][dk] * Q[j][dk]
        float16v C;
        #pragma unroll
        for (int i = 0; i < 16; ++i) C[i] = 0.f;
        const int am = dvh * 32 + (lane & 31);
        const int bn = jh  * 32 + (lane & 31);
        #pragma unroll
        for (int ks = 0; ks < 4; ++ks) {
            int ch = ks * 2 + (lane >> 5);
            bf16x8 af = *(const bf16x8*)&M_bf[am * 64 + ((ch ^ (am & 7)) << 3)];
            bf16x8 bf = *(const bf16x8*)&Q_bf[bn * 64 + ((ch ^ (bn & 7)) << 3)];
            C = __builtin_amdgcn_mfma_f32_32x32x16_bf16(af, bf, C, 0, 0, 0);
        }
        // epilogue: scale by w/den, write to O[j][dv] (stride 66)
        {
            double den = den_s[bn];
            float  w   = w_s[bn];
            float rinv = (float)((double)w / (den + (double)EPS));
            #pragma unroll
            for (int r = 0; r < 16; ++r) {
                int dv = dvh * 32 + (r & 3) + 8 * (r >> 2) + 4 * (lane >> 5);
                Ou[bn * 66 + dv] = C[r] * rinv;
            }
        }
        __syncthreads();

        // flush: one coalesced atomic inst per query row
        #pragma unroll
        for (int jj = 0; jj < 16; ++jj) {
            int j = grp * 16 + jj;
            if (j < nb) {
                float v = Ou[j * 66 + lane];
                unsafeAtomicAdd(&ob[(size_t)sq_s[j] * 64 + lane], v);
            }
        }
    }
}

extern "C" void kernel_launch(void* const* d_in, const int* in_sizes, int n_in,
                              void* d_out, int out_size, void* d_ws, size_t ws_size,
                              hipStream_t stream) {
    const float* keys    = (const float*)d_in[0];
    const float* values  = (const float*)d_in[1];
    const float* queries = (const float*)d_in[2];
    char* ws = (char*)d_ws;
    int*            kcnt  = (int*)(ws);
    int*            qcnt  = (int*)(ws + 8192);
    unsigned short* klist = (unsigned short*)(ws + 16384);
    int2*           qpair = (int2*)(ws + 4210688);

    hipMemsetAsync(ws, 0, 16384, stream);
    hipMemsetAsync(d_out, 0, (size_t)out_size * sizeof(float), stream);
    k_assign<<<8192, 256, 0, stream>>>(keys, kcnt, klist);
    k_topk  <<<8192, 256, 0, stream>>>(queries, qcnt, qpair);
    k_main  <<<4096, 256, 0, stream>>>(keys, values, queries, kcnt, klist, qcnt, qpair,
                                       (float*)d_out);
}

// Round 4
// 227.194 us; speedup vs baseline: 1.9153x; 1.0736x over previous
//
#include <hip/hip_runtime.h>
#include <math.h>

#define S_LEN 1024
#define EPS 1e-6f

typedef __attribute__((ext_vector_type(8)))  short bf16x8;
typedef __attribute__((ext_vector_type(16))) float float16v;

// Workspace layout (bytes):
//   kcnt  : int    [2048]        @ 0
//   qcnt  : int    [2048]        @ 8192
//   klist : ushort [2048*1024]   @ 16384      (4 MB)
//   qpair : int2   [2048*1024]   @ 4210688    (16 MB)

__device__ __forceinline__ void wave_argmax(float& bv, int& bi) {
    #pragma unroll
    for (int off = 1; off < 64; off <<= 1) {
        float ov = __shfl_xor(bv, off, 64);
        int   oi = __shfl_xor(bi, off, 64);
        if (ov > bv || (ov == bv && oi < bi)) { bv = ov; bi = oi; }
    }
}

__device__ __forceinline__ unsigned short f2bf(float f) {
    unsigned int u = __float_as_uint(f);
    unsigned int r = (u + 0x7fffu + ((u >> 16) & 1u)) >> 16;
    return (unsigned short)r;
}

__device__ __forceinline__ bf16x8 pack8(float4 a, float4 b) {
    bf16x8 r;
    r[0] = (short)f2bf(a.x); r[1] = (short)f2bf(a.y);
    r[2] = (short)f2bf(a.z); r[3] = (short)f2bf(a.w);
    r[4] = (short)f2bf(b.x); r[5] = (short)f2bf(b.y);
    r[6] = (short)f2bf(b.z); r[7] = (short)f2bf(b.w);
    return r;
}

// one wave per key: bank = argmax_d |k_d|; scatter s into per-(bh,bank) list
__global__ __launch_bounds__(256) void k_assign(const float* __restrict__ keys,
                                                int* __restrict__ kcnt,
                                                unsigned short* __restrict__ klist) {
    int gid  = blockIdx.x * 4 + (threadIdx.x >> 6);
    int lane = threadIdx.x & 63;
    float bv = fabsf(keys[(size_t)gid * 64 + lane]);
    int bi = lane;
    wave_argmax(bv, bi);
    if (lane == 0) {
        int g = (gid >> 10) * 64 + bi;
        int p = atomicAdd(&kcnt[g], 1);
        klist[(size_t)g * 1024 + p] = (unsigned short)(gid & 1023);
    }
}

// one wave per query. Exact duplicated-top-16 via RANK COUNTING: with the
// stable key ordering (value desc, dim asc), lane d's low copy sits at
// duplicated-array position r+gt and its high copy at r+gt+eq, where
//   r  = # lanes with greater (value,dim)-key
//   gt = # lanes with strictly greater value
//   eq = # lanes with equal value (incl. self)
// Contributes iff pos_low < 16; softmax sum = wave-sum of copies*exp(val).
// One unrolled loop of independent VALU ops -- no dependent shuffle chains.
__global__ __launch_bounds__(256) void k_topk(const float* __restrict__ queries,
                                              int* __restrict__ qcnt,
                                              int2* __restrict__ qpair) {
    int gid  = blockIdx.x * 4 + (threadIdx.x >> 6);
    int lane = threadIdx.x & 63;
    unsigned ud = __float_as_uint(queries[(size_t)gid * 64 + lane]) & 0x7fffffffu;
    unsigned long long kd = ((unsigned long long)ud << 32) | (unsigned)(63 - lane);
    int r = 0, gt = 0, eq = 0;
    #pragma unroll
    for (int i = 0; i < 64; ++i) {
        unsigned ui = (unsigned)__builtin_amdgcn_readlane((int)ud, i);
        unsigned long long ki = ((unsigned long long)ui << 32) | (unsigned)(63 - i);
        r  += (ki > kd) ? 1 : 0;
        gt += (ui > ud) ? 1 : 0;
        eq += (ui == ud) ? 1 : 0;
    }
    int pos_low  = r + gt;
    int pos_high = pos_low + eq;
    int copies   = (pos_low < 16 ? 1 : 0) + (pos_high < 16 ? 1 : 0);
    float e  = expf(__uint_as_float(ud));          // |q| <= ~6, no overflow
    float ce = (float)copies * e;
    #pragma unroll
    for (int off = 1; off < 64; off <<= 1) ce += __shfl_xor(ce, off, 64);
    if (pos_low < 16) {
        int bh = gid >> 10, s = gid & 1023;
        int g = bh * 64 + lane;                    // dim == lane
        int pos = atomicAdd(&qcnt[g], 1);
        int2 pr; pr.x = s; pr.y = __float_as_int(e / ce);
        qpair[(size_t)g * 1024 + pos] = pr;
    }
}

// one block per (bh, bank, chunk): build M(64x64)->bf16 LDS + z fp32, then per
// 64-query batch: stage Q as bf16 (den folded into staging, fp64), 4 MFMAs per
// wave, transpose O through LDS, coalesced atomic flush.
__global__ __launch_bounds__(256) void k_main(const float* __restrict__ keys,
                                              const float* __restrict__ values,
                                              const float* __restrict__ queries,
                                              const int* __restrict__ kcnt,
                                              const unsigned short* __restrict__ klist,
                                              const int* __restrict__ qcnt,
                                              const int2* __restrict__ qpair,
                                              float* __restrict__ out) {
    const int gc    = blockIdx.x;      // 0..4095
    const int g     = gc >> 1;
    const int chunk = gc & 1;
    const int bh    = g >> 6;
    const int t     = threadIdx.x;
    const int lane  = t & 63;
    const int grp   = t >> 6;

    __shared__ alignas(16) unsigned short M_bf[64 * 64];   // swizzled 16B chunks
    __shared__ alignas(16) unsigned short Q_bf[64 * 64];   // swizzled 16B chunks
    __shared__ alignas(16) float Ou[64 * 66];              // O transpose / kv staging
    __shared__ float  z_s[64];
    __shared__ double den_s[64];
    __shared__ float  w_s[64];
    __shared__ int    sq_s[64];

    const int nq_all = qcnt[g];
    if (nq_all == 0) return;
    const int half = (nq_all + 1) >> 1;
    const int q_lo = chunk * half;
    const int nq   = min(nq_all, q_lo + half) - q_lo;
    if (nq <= 0) return;
    const int nm = kcnt[g];
    if (nm == 0) return;               // M=0, z=0 -> exact zero contribution

    // ---- build M[dv][dk] = sum_s v[dv]*k[dk], z[dk] = sum_s k[dk] (fp32) ----
    float* kst = Ou;                   // [8][64]
    float* vst = Ou + 512;             // [8][64]
    float acc[16];
    #pragma unroll
    for (int m = 0; m < 16; ++m) acc[m] = 0.f;
    float zacc = 0.f;
    const float* kb = keys   + (size_t)bh * S_LEN * 64;
    const float* vb = values + (size_t)bh * S_LEN * 64;
    const unsigned short* kl = klist + (size_t)g * 1024;
    for (int base = 0; base < nm; base += 8) {
        __syncthreads();
        #pragma unroll
        for (int rr = 0; rr < 2; ++rr) {
            int row = grp + rr * 4;
            if (base + row < nm) {
                int s = kl[base + row];
                kst[row * 64 + lane] = kb[(size_t)s * 64 + lane];
                vst[row * 64 + lane] = vb[(size_t)s * 64 + lane];
            }
        }
        __syncthreads();
        int lim = min(8, nm - base);
        for (int jj = 0; jj < lim; ++jj) {
            float kv = kst[jj * 64 + lane];            // dk = lane
            #pragma unroll
            for (int m = 0; m < 16; ++m)               // dv = grp*16+m
                acc[m] += vst[jj * 64 + grp * 16 + m] * kv;
        }
        if (t < 64)
            for (int jj = 0; jj < lim; ++jj) zacc += kst[jj * 64 + t];
    }
    // write M as bf16, row-major [dv][dk], 16B-chunk XOR swizzle
    #pragma unroll
    for (int m = 0; m < 16; ++m) {
        int dv = grp * 16 + m;
        M_bf[dv * 64 + (((lane >> 3) ^ (dv & 7)) << 3) + (lane & 7)] = f2bf(acc[m]);
    }
    if (t < 64) z_s[t] = zacc;

    // ---- query phase ----
    const float* qb  = queries + (size_t)bh * S_LEN * 64;
    float*       ob  = out     + (size_t)bh * S_LEN * 64;
    const int2*  ql2 = qpair + (size_t)g * 1024 + q_lo;

    const int dvh = grp >> 1, jh = grp & 1;            // wave's 32x32 tile

    for (int qbase = 0; qbase < nq; qbase += 64) {
        const int nb = min(64, nq - qbase);
        __syncthreads();               // M_bf/z_s visible; prev flush done

        // stage: thread -> (query j = t>>2, 16-float slice c4 = t&3)
        {
            int j = t >> 2, c4 = t & 3;
            bf16x8 p0 = {}, p1 = {};
            double d = 0.0;
            if (j < nb) {
                int s = ql2[qbase + j].x;
                const float4* src = (const float4*)(qb + (size_t)s * 64 + c4 * 16);
                float4 f0 = src[0], f1 = src[1], f2 = src[2], f3 = src[3];
                p0 = pack8(f0, f1);
                p1 = pack8(f2, f3);
                const float4* zz4 = (const float4*)&z_s[c4 * 16];
                float4 z0 = zz4[0], z1 = zz4[1], z2 = zz4[2], z3 = zz4[3];
                d  = (double)z0.x * f0.x + (double)z0.y * f0.y + (double)z0.z * f0.z + (double)z0.w * f0.w;
                d += (double)z1.x * f1.x + (double)z1.y * f1.y + (double)z1.z * f1.z + (double)z1.w * f1.w;
                d += (double)z2.x * f2.x + (double)z2.y * f2.y + (double)z2.z * f2.z + (double)z2.w * f2.w;
                d += (double)z3.x * f3.x + (double)z3.y * f3.y + (double)z3.z * f3.z + (double)z3.w * f3.w;
            }
            int c0 = c4 * 2;
            *(bf16x8*)&Q_bf[j * 64 + ((c0 ^ (j & 7)) << 3)]       = p0;
            *(bf16x8*)&Q_bf[j * 64 + (((c0 + 1) ^ (j & 7)) << 3)] = p1;
            d += __shfl_xor(d, 1, 64);
            d += __shfl_xor(d, 2, 64);
            if ((t & 3) == 0) den_s[j] = d;
            if (t < 64) {
                if (t < nb) {
                    int2 pr = ql2[qbase + t];
                    sq_s[t] = pr.x; w_s[t] = __int_as_float(pr.y);
                } else { sq_s[t] = 0; w_s[t] = 0.f; }
            }
        }
        __syncthreads();

        // MFMA: O[dv][j] = sum_dk M[dv][dk] * Q[j][dk]
        float16v C;
        #pragma unroll
        for (int i = 0; i < 16; ++i) C[i] = 0.f;
        const int am = dvh * 32 + (lane & 31);
        const int bn = jh  * 32 + (lane & 31);
        #pragma unroll
        for (int ks = 0; ks < 4; ++ks) {
            int ch = ks * 2 + (lane >> 5);
            bf16x8 af = *(const bf16x8*)&M_bf[am * 64 + ((ch ^ (am & 7)) << 3)];
            bf16x8 bf = *(const bf16x8*)&Q_bf[bn * 64 + ((ch ^ (bn & 7)) << 3)];
            C = __builtin_amdgcn_mfma_f32_32x32x16_bf16(af, bf, C, 0, 0, 0);
        }
        // epilogue: scale by w/den, write to O[j][dv] (stride 66)
        {
            double den = den_s[bn];
            float  w   = w_s[bn];
            float rinv = (float)((double)w / (den + (double)EPS));
            #pragma unroll
            for (int r = 0; r < 16; ++r) {
                int dv = dvh * 32 + (r & 3) + 8 * (r >> 2) + 4 * (lane >> 5);
                Ou[bn * 66 + dv] = C[r] * rinv;
            }
        }
        __syncthreads();

        // flush: one coalesced atomic inst per query row
        #pragma unroll
        for (int jj = 0; jj < 16; ++jj) {
            int j = grp * 16 + jj;
            if (j < nb) {
                float v = Ou[j * 66 + lane];
                unsafeAtomicAdd(&ob[(size_t)sq_s[j] * 64 + lane], v);
            }
        }
    }
}

extern "C" void kernel_launch(void* const* d_in, const int* in_sizes, int n_in,
                              void* d_out, int out_size, void* d_ws, size_t ws_size,
                              hipStream_t stream) {
    const float* keys    = (const float*)d_in[0];
    const float* values  = (const float*)d_in[1];
    const float* queries = (const float*)d_in[2];
    char* ws = (char*)d_ws;
    int*            kcnt  = (int*)(ws);
    int*            qcnt  = (int*)(ws + 8192);
    unsigned short* klist = (unsigned short*)(ws + 16384);
    int2*           qpair = (int2*)(ws + 4210688);

    hipMemsetAsync(ws, 0, 16384, stream);
    hipMemsetAsync(d_out, 0, (size_t)out_size * sizeof(float), stream);
    k_assign<<<8192, 256, 0, stream>>>(keys, kcnt, klist);
    k_topk  <<<8192, 256, 0, stream>>>(queries, qcnt, qpair);
    k_main  <<<4096, 256, 0, stream>>>(keys, values, queries, kcnt, klist, qcnt, qpair,
                                       (float*)d_out);
}

// Round 5
// 200.658 us; speedup vs baseline: 2.1686x; 1.1322x over previous
//
#include <hip/hip_runtime.h>
#include <math.h>

#define S_LEN 1024
#define EPS 1e-6f

typedef __attribute__((ext_vector_type(8)))  short bf16x8;
typedef __attribute__((ext_vector_type(16))) float float16v;

// Workspace layout (bytes):
//   kcnt  : int  [2048]           @ 0          (8192)
//   qcnt2 : int  [32*32*64]       @ 8192       (262144)   per (bh, seg, dim)
//   klist : ushort [2048*1024]    @ 270336     (4194304)
//   qpair : uint [2048*1024]      @ 4464640    (8388608)  packed (w_hi22 | s_10)

__device__ __forceinline__ void wave_argmax(float& bv, int& bi) {
    #pragma unroll
    for (int off = 1; off < 64; off <<= 1) {
        float ov = __shfl_xor(bv, off, 64);
        int   oi = __shfl_xor(bi, off, 64);
        if (ov > bv || (ov == bv && oi < bi)) { bv = ov; bi = oi; }
    }
}

__device__ __forceinline__ unsigned short f2bf(float f) {
    unsigned int u = __float_as_uint(f);
    unsigned int r = (u + 0x7fffu + ((u >> 16) & 1u)) >> 16;
    return (unsigned short)r;
}

__device__ __forceinline__ bf16x8 pack8(float4 a, float4 b) {
    bf16x8 r;
    r[0] = (short)f2bf(a.x); r[1] = (short)f2bf(a.y);
    r[2] = (short)f2bf(a.z); r[3] = (short)f2bf(a.w);
    r[4] = (short)f2bf(b.x); r[5] = (short)f2bf(b.y);
    r[6] = (short)f2bf(b.z); r[7] = (short)f2bf(b.w);
    return r;
}

// one wave per key: bank = argmax_d |k_d|; scatter s into per-(bh,bank) list
__global__ __launch_bounds__(256) void k_assign(const float* __restrict__ keys,
                                                int* __restrict__ kcnt,
                                                unsigned short* __restrict__ klist) {
    int gid  = blockIdx.x * 4 + (threadIdx.x >> 6);
    int lane = threadIdx.x & 63;
    float bv = fabsf(keys[(size_t)gid * 64 + lane]);
    int bi = lane;
    wave_argmax(bv, bi);
    if (lane == 0) {
        int g = (gid >> 10) * 64 + bi;
        int p = atomicAdd(&kcnt[g], 1);
        klist[(size_t)g * 1024 + p] = (unsigned short)(gid & 1023);
    }
}

// 1024 blocks x 256 threads; block = (bh, seg) handles 32 queries and OWNS the
// 32-slot segment `seg` of every bank list (32 seg x 32 = 1024 capacity: exact
// worst case, no overflow, NO global atomics). Exact duplicated-top-16 by rank
// counting: pos_low = 2*gt + eql, pos_high = pos_low + eq (stable tie order).
// Position within segment from an LDS histogram.
__global__ __launch_bounds__(256) void k_topk(const float* __restrict__ queries,
                                              int* __restrict__ qcnt2,
                                              unsigned* __restrict__ qpair) {
    const int bh   = blockIdx.x >> 5;
    const int blk  = blockIdx.x & 31;          // segment id
    const int wv   = threadIdx.x >> 6;
    const int lane = threadIdx.x & 63;

    __shared__ int hist[64];
    if (threadIdx.x < 64) hist[threadIdx.x] = 0;
    __syncthreads();

    for (int qq = 0; qq < 8; ++qq) {
        int s   = blk * 32 + wv * 8 + qq;      // in-bh query index
        int gid = bh * 1024 + s;
        unsigned ud = __float_as_uint(queries[(size_t)gid * 64 + lane]) & 0x7fffffffu;
        int gt = 0, eq = 0;
        unsigned em_lo = 0, em_hi = 0;
        #pragma unroll
        for (int i = 0; i < 64; ++i) {
            unsigned ui = (unsigned)__builtin_amdgcn_readlane((int)ud, i);
            gt += (ui > ud) ? 1 : 0;
            unsigned iseq = (ui == ud) ? 1u : 0u;
            eq += (int)iseq;
            if (i < 32) em_lo |= iseq << i; else em_hi |= iseq << (i - 32);
        }
        unsigned long long em = ((unsigned long long)em_hi << 32) | em_lo;
        int eql = __popcll(em & ((1ull << lane) - 1ull));   // equal, smaller dim
        int pos_low  = 2 * gt + eql;
        int pos_high = pos_low + eq;           // eq includes self
        int copies   = (pos_low < 16 ? 1 : 0) + (pos_high < 16 ? 1 : 0);
        float e  = expf(__uint_as_float(ud));  // |q| small: no overflow
        float ce = (float)copies * e;
        #pragma unroll
        for (int off = 1; off < 64; off <<= 1) ce += __shfl_xor(ce, off, 64);
        if (pos_low < 16) {
            int pos = atomicAdd(&hist[lane], 1);            // LDS atomic
            unsigned wb = __float_as_uint(e / ce) & 0xFFFFFC00u;
            qpair[(size_t)(bh * 64 + lane) * 1024 + blk * 32 + pos] =
                wb | (unsigned)s;
        }
    }
    __syncthreads();
    if (threadIdx.x < 64)
        qcnt2[(bh * 32 + blk) * 64 + threadIdx.x] = hist[threadIdx.x];
}

// one block per (bh, bank, chunk): build M(64x64)->bf16 LDS + z fp32, then per
// 64-query batch: fetch packed entries via segment search, stage Q as bf16
// (fp64 den folded into staging), 4 MFMAs/wave, transpose O via LDS, flush.
__global__ __launch_bounds__(256) void k_main(const float* __restrict__ keys,
                                              const float* __restrict__ values,
                                              const float* __restrict__ queries,
                                              const int* __restrict__ kcnt,
                                              const unsigned short* __restrict__ klist,
                                              const int* __restrict__ qcnt2,
                                              const unsigned* __restrict__ qpair,
                                              float* __restrict__ out) {
    const int gc    = blockIdx.x;      // 0..4095
    const int g     = gc >> 1;
    const int chunk = gc & 1;
    const int bh    = g >> 6;
    const int bank  = g & 63;
    const int t     = threadIdx.x;
    const int lane  = t & 63;
    const int grp   = t >> 6;

    __shared__ alignas(16) unsigned short M_bf[64 * 64];   // swizzled 16B chunks
    __shared__ alignas(16) unsigned short Q_bf[64 * 64];   // swizzled 16B chunks
    __shared__ alignas(16) float Ou[64 * 66];              // O transpose / kv staging
    __shared__ float  z_s[64];
    __shared__ double den_s[64];
    __shared__ float  w_s[64];
    __shared__ int    sq_s[64];

    // segment prefix (uniform across block -> scalar loads)
    int offs[32];
    int run = 0;
    #pragma unroll
    for (int i = 0; i < 32; ++i) {
        offs[i] = run;
        run += qcnt2[(bh * 32 + i) * 64 + bank];
    }
    const int nq_all = run;
    if (nq_all == 0) return;
    const int half = (nq_all + 1) >> 1;
    const int q_lo = chunk * half;
    const int nq   = min(nq_all, q_lo + half) - q_lo;
    if (nq <= 0) return;
    const int nm = kcnt[g];
    if (nm == 0) return;               // M=0, z=0 -> exact zero contribution

    // ---- build M[dv][dk] = sum_s v[dv]*k[dk], z[dk] = sum_s k[dk] (fp32) ----
    float* kst = Ou;                   // [8][64]
    float* vst = Ou + 512;             // [8][64]
    float acc[16];
    #pragma unroll
    for (int m = 0; m < 16; ++m) acc[m] = 0.f;
    float zacc = 0.f;
    const float* kb = keys   + (size_t)bh * S_LEN * 64;
    const float* vb = values + (size_t)bh * S_LEN * 64;
    const unsigned short* kl = klist + (size_t)g * 1024;
    for (int base = 0; base < nm; base += 8) {
        __syncthreads();
        #pragma unroll
        for (int rr = 0; rr < 2; ++rr) {
            int row = grp + rr * 4;
            if (base + row < nm) {
                int s = kl[base + row];
                kst[row * 64 + lane] = kb[(size_t)s * 64 + lane];
                vst[row * 64 + lane] = vb[(size_t)s * 64 + lane];
            }
        }
        __syncthreads();
        int lim = min(8, nm - base);
        for (int jj = 0; jj < lim; ++jj) {
            float kv = kst[jj * 64 + lane];            // dk = lane
            #pragma unroll
            for (int m = 0; m < 16; ++m)               // dv = grp*16+m
                acc[m] += vst[jj * 64 + grp * 16 + m] * kv;
        }
        if (t < 64)
            for (int jj = 0; jj < lim; ++jj) zacc += kst[jj * 64 + t];
    }
    // write M as bf16, row-major [dv][dk], 16B-chunk XOR swizzle
    #pragma unroll
    for (int m = 0; m < 16; ++m) {
        int dv = grp * 16 + m;
        M_bf[dv * 64 + (((lane >> 3) ^ (dv & 7)) << 3) + (lane & 7)] = f2bf(acc[m]);
    }
    if (t < 64) z_s[t] = zacc;

    // ---- query phase ----
    const float* qb = queries + (size_t)bh * S_LEN * 64;
    float*       ob = out     + (size_t)bh * S_LEN * 64;

    const int dvh = grp >> 1, jh = grp & 1;            // wave's 32x32 tile

    for (int qbase = 0; qbase < nq; qbase += 64) {
        const int nb = min(64, nq - qbase);
        __syncthreads();               // (A) M/z visible; prev flush done

        // phase 1: t<64 fetch packed entries via segment search
        if (t < 64) {
            if (t < nb) {
                int jg = q_lo + qbase + t;
                int seg = 0, segbase = 0;
                #pragma unroll
                for (int i = 1; i < 32; ++i)
                    if (jg >= offs[i]) { seg = i; segbase = offs[i]; }
                unsigned e = qpair[(size_t)g * 1024 + seg * 32 + (jg - segbase)];
                sq_s[t] = (int)(e & 1023u);
                w_s[t]  = __uint_as_float(e & 0xFFFFFC00u);
            } else { sq_s[t] = 0; w_s[t] = 0.f; }
        }
        __syncthreads();               // (B) entries visible

        // phase 2: stage Q bf16 + fp64 den; thread -> (j = t>>2, slice c4)
        {
            int j = t >> 2, c4 = t & 3;
            bf16x8 p0 = {}, p1 = {};
            double d = 0.0;
            if (j < nb) {
                int s = sq_s[j];
                const float4* src = (const float4*)(qb + (size_t)s * 64 + c4 * 16);
                float4 f0 = src[0], f1 = src[1], f2 = src[2], f3 = src[3];
                p0 = pack8(f0, f1);
                p1 = pack8(f2, f3);
                const float4* zz4 = (const float4*)&z_s[c4 * 16];
                float4 z0 = zz4[0], z1 = zz4[1], z2 = zz4[2], z3 = zz4[3];
                d  = (double)z0.x * f0.x + (double)z0.y * f0.y + (double)z0.z * f0.z + (double)z0.w * f0.w;
                d += (double)z1.x * f1.x + (double)z1.y * f1.y + (double)z1.z * f1.z + (double)z1.w * f1.w;
                d += (double)z2.x * f2.x + (double)z2.y * f2.y + (double)z2.z * f2.z + (double)z2.w * f2.w;
                d += (double)z3.x * f3.x + (double)z3.y * f3.y + (double)z3.z * f3.z + (double)z3.w * f3.w;
            }
            int c0 = c4 * 2;
            *(bf16x8*)&Q_bf[j * 64 + ((c0 ^ (j & 7)) << 3)]       = p0;
            *(bf16x8*)&Q_bf[j * 64 + (((c0 + 1) ^ (j & 7)) << 3)] = p1;
            d += __shfl_xor(d, 1, 64);
            d += __shfl_xor(d, 2, 64);
            if ((t & 3) == 0) den_s[j] = d;
        }
        __syncthreads();               // (C)

        // MFMA: O[dv][j] = sum_dk M[dv][dk] * Q[j][dk]
        float16v C;
        #pragma unroll
        for (int i = 0; i < 16; ++i) C[i] = 0.f;
        const int am = dvh * 32 + (lane & 31);
        const int bn = jh  * 32 + (lane & 31);
        #pragma unroll
        for (int ks = 0; ks < 4; ++ks) {
            int ch = ks * 2 + (lane >> 5);
            bf16x8 af = *(const bf16x8*)&M_bf[am * 64 + ((ch ^ (am & 7)) << 3)];
            bf16x8 bf = *(const bf16x8*)&Q_bf[bn * 64 + ((ch ^ (bn & 7)) << 3)];
            C = __builtin_amdgcn_mfma_f32_32x32x16_bf16(af, bf, C, 0, 0, 0);
        }
        // epilogue: scale by w/den, write O[j][dv] (stride 66)
        {
            double den = den_s[bn];
            float  w   = w_s[bn];
            float rinv = (float)((double)w / (den + (double)EPS));
            #pragma unroll
            for (int r = 0; r < 16; ++r) {
                int dv = dvh * 32 + (r & 3) + 8 * (r >> 2) + 4 * (lane >> 5);
                Ou[bn * 66 + dv] = C[r] * rinv;
            }
        }
        __syncthreads();               // (D)

        // flush: one coalesced atomic inst per query row
        #pragma unroll
        for (int jj = 0; jj < 16; ++jj) {
            int j = grp * 16 + jj;
            if (j < nb) {
                float v = Ou[j * 66 + lane];
                unsafeAtomicAdd(&ob[(size_t)sq_s[j] * 64 + lane], v);
            }
        }
    }
}

extern "C" void kernel_launch(void* const* d_in, const int* in_sizes, int n_in,
                              void* d_out, int out_size, void* d_ws, size_t ws_size,
                              hipStream_t stream) {
    const float* keys    = (const float*)d_in[0];
    const float* values  = (const float*)d_in[1];
    const float* queries = (const float*)d_in[2];
    char* ws = (char*)d_ws;
    int*            kcnt  = (int*)(ws);
    int*            qcnt2 = (int*)(ws + 8192);
    unsigned short* klist = (unsigned short*)(ws + 270336);
    unsigned*       qpair = (unsigned*)(ws + 4464640);

    hipMemsetAsync(ws, 0, 270336, stream);
    hipMemsetAsync(d_out, 0, (size_t)out_size * sizeof(float), stream);
    k_assign<<<8192, 256, 0, stream>>>(keys, kcnt, klist);
    k_topk  <<<1024, 256, 0, stream>>>(queries, qcnt2, qpair);
    k_main  <<<4096, 256, 0, stream>>>(keys, values, queries, kcnt, klist, qcnt2, qpair,
                                       (float*)d_out);
}